// Round 4
// baseline (1050.714 us; speedup 1.0000x reference)
//
#include <hip/hip_runtime.h>
#include <hip/hip_cooperative_groups.h>
#include <math.h>

namespace cg = cooperative_groups;

#define NN 10000
#define DD 256
#define QQ 4096
#define CAP 128     // max neighbors kept per row; Binom(10000,0.003) tail @128 ~ 0
#define NB 1024     // fused grid: 1024 blocks x 256 thr = 4096 waves (4 blocks/CU)

typedef float  fx4 __attribute__((ext_vector_type(4)));

// ws layout:
//   float xn[NN*DD]      normalized x rows
//   int   cnt[NN]        TRUE neighbor count per row (consumers clamp to CAP)
//   int   nbr[NN*CAP]    neighbor indices per row (arbitrary order)

// ---------------------------------------------------------------------------
// Fused single-dispatch version: scan -> grid.sync -> gather -> grid.sync ->
// edges. Eliminates inter-kernel serialization/drain, and (deliberately) makes
// one >244us dispatch so rocprof top-5 finally shows OUR counters.
// ---------------------------------------------------------------------------
__global__ __launch_bounds__(256) void fused(
    const float* __restrict__ emb, const float* __restrict__ adj,
    const int* __restrict__ edges, float* __restrict__ out,
    float* __restrict__ xn, int* __restrict__ cnt, int* __restrict__ nbr)
{
    cg::grid_group grid = cg::this_grid();
    const int t    = threadIdx.x;
    const int lane = t & 63;
    const int wv   = t >> 6;

    __shared__ int   s_list[CAP];
    __shared__ float s_red[4];
    __shared__ float s_norm;
    __shared__ int   s_dst[4][CAP];
    __shared__ int   s_com[4][CAP];
    __shared__ int   s_nc[4];

    // ===== phase 1: wave-per-row ballot scan (r2 structure, tied-best) =====
    {
        const int wid = (blockIdx.x << 2) | wv;
        const unsigned long long lmask = (1ull << lane) - 1ull;

        for (int row = wid; row < NN; row += (NB << 2)) {
            const fx4* rp  = (const fx4*)(adj + (size_t)row * NN);   // 2500 fx4/row
            int* outp = nbr + (size_t)row * CAP;
            int base = 0;

            fx4 b0 = __builtin_nontemporal_load(&rp[lane]);
            fx4 b1 = __builtin_nontemporal_load(&rp[64  + lane]);
            fx4 b2 = __builtin_nontemporal_load(&rp[128 + lane]);
            fx4 b3 = __builtin_nontemporal_load(&rp[192 + lane]);

            #define CKCOMP(val, col)                                              \
                { unsigned long long _b = __ballot((val) != 0.f);                 \
                  if ((val) != 0.f) {                                             \
                      int _p = base + (int)__popcll(_b & lmask);                  \
                      if (_p < CAP) outp[_p] = (col);                             \
                  }                                                               \
                  base += (int)__popcll(_b); }

            #define CKCHUNK(v, cidx)                                              \
                { int _cb = (cidx) * 256 + lane * 4;                              \
                  CKCOMP(v.x, _cb); CKCOMP(v.y, _cb + 1);                         \
                  CKCOMP(v.z, _cb + 2); CKCOMP(v.w, _cb + 3); }

            for (int cc = 0; cc < 40; cc += 4) {
                fx4 v0 = b0, v1 = b1, v2 = b2, v3 = b3;
                int n0 = (cc + 4) * 64 + lane;
                int n1 = (cc + 5) * 64 + lane;
                int n2 = (cc + 6) * 64 + lane;
                int n3 = (cc + 7) * 64 + lane;
                b0 = (n0 < 2500) ? __builtin_nontemporal_load(&rp[n0]) : (fx4){0.f,0.f,0.f,0.f};
                b1 = (n1 < 2500) ? __builtin_nontemporal_load(&rp[n1]) : (fx4){0.f,0.f,0.f,0.f};
                b2 = (n2 < 2500) ? __builtin_nontemporal_load(&rp[n2]) : (fx4){0.f,0.f,0.f,0.f};
                b3 = (n3 < 2500) ? __builtin_nontemporal_load(&rp[n3]) : (fx4){0.f,0.f,0.f,0.f};
                CKCHUNK(v0, cc);
                CKCHUNK(v1, cc + 1);
                CKCHUNK(v2, cc + 2);
                CKCHUNK(v3, cc + 3);
            }
            #undef CKCHUNK
            #undef CKCOMP

            if (lane == 0) cnt[row] = base;
        }
    }
    __threadfence();
    grid.sync();

    // ===== phase 2: gather + normalize (block-per-row, grid-stride) =====
    for (int i = blockIdx.x; i < NN; i += NB) {
        const int c = cnt[i];
        const int m = (c < CAP) ? c : CAP;

        const float self = emb[(size_t)i * DD + t];
        if (t < m) s_list[t] = nbr[(size_t)i * CAP + t];
        __syncthreads();

        float a0=0.f,a1=0.f,a2=0.f,a3=0.f,a4=0.f,a5=0.f,a6=0.f,a7=0.f;
        int k = 0;
        for (; k + 8 <= m; k += 8) {
            int i0=s_list[k],   i1=s_list[k+1], i2=s_list[k+2], i3=s_list[k+3];
            int i4=s_list[k+4], i5=s_list[k+5], i6=s_list[k+6], i7=s_list[k+7];
            a0 += emb[(size_t)i0*DD + t]; a1 += emb[(size_t)i1*DD + t];
            a2 += emb[(size_t)i2*DD + t]; a3 += emb[(size_t)i3*DD + t];
            a4 += emb[(size_t)i4*DD + t]; a5 += emb[(size_t)i5*DD + t];
            a6 += emb[(size_t)i6*DD + t]; a7 += emb[(size_t)i7*DD + t];
        }
        for (; k < m; ++k) a0 += emb[(size_t)s_list[k]*DD + t];
        const float acc = ((a0+a1)+(a2+a3)) + ((a4+a5)+(a6+a7));

        const float deg = (float)c + 1e-6f;
        const float x = self + acc / deg;

        float s = x * x;
        #pragma unroll
        for (int o = 32; o > 0; o >>= 1) s += __shfl_down(s, o, 64);
        if (lane == 0) s_red[wv] = s;
        __syncthreads();
        if (t == 0) {
            float tot = s_red[0] + s_red[1] + s_red[2] + s_red[3];
            s_norm = fmaxf(sqrtf(tot), 1e-8f);
        }
        __syncthreads();

        xn[(size_t)i * DD + t] = x / s_norm;
        __syncthreads();   // s_list/s_red reuse guard for next row
    }
    __threadfence();
    grid.sync();

    // ===== phase 3: edge weights (wave-per-edge; 4096 waves == QQ) =====
    {
        const int e = (blockIdx.x << 2) | wv;           // exact cover of [0,4096)
        const int srcI = edges[e];
        const int dstI = edges[QQ + e];

        const int2 sA = ((const int2*)(nbr + (size_t)srcI * CAP))[lane];
        const int2 dA = ((const int2*)(nbr + (size_t)dstI * CAP))[lane];
        int cs = cnt[srcI]; cs = (cs < CAP) ? cs : CAP;
        int cd = cnt[dstI]; cd = (cd < CAP) ? cd : CAP;

        if (lane == 0) s_nc[wv] = 0;
        s_dst[wv][2 * lane]     = dA.x;
        s_dst[wv][2 * lane + 1] = dA.y;
        __syncthreads();

        {
            int k0 = 2 * lane, k1 = 2 * lane + 1;
            if (k0 < cs) {
                bool f = false;
                for (int j = 0; j < cd; ++j) { if (s_dst[wv][j] == sA.x) { f = true; break; } }
                if (f) { int p = atomicAdd(&s_nc[wv], 1); s_com[wv][p] = sA.x; }
            }
            if (k1 < cs) {
                bool f = false;
                for (int j = 0; j < cd; ++j) { if (s_dst[wv][j] == sA.y) { f = true; break; } }
                if (f) { int p = atomicAdd(&s_nc[wv], 1); s_com[wv][p] = sA.y; }
            }
        }
        __syncthreads();

        const int nc = s_nc[wv];
        if (nc == 0) {
            if (lane == 0) out[e] = 0.5f;
        } else {
            const float4 vs = ((const float4*)(xn + (size_t)srcI * DD))[lane];
            const float4 vd = ((const float4*)(xn + (size_t)dstI * DD))[lane];
            float w = 0.f;
            for (int q = 0; q < nc; ++q) {
                const float4 vc = ((const float4*)(xn + (size_t)s_com[wv][q] * DD))[lane];
                float a = vs.x*vc.x + vs.y*vc.y + vs.z*vc.z + vs.w*vc.w;
                float b = vd.x*vc.x + vd.y*vc.y + vd.z*vc.z + vd.w*vc.w;
                #pragma unroll
                for (int o = 32; o > 0; o >>= 1) {
                    a += __shfl_xor(a, o, 64);
                    b += __shfl_xor(b, o, 64);
                }
                w += a * b;
            }
            if (lane == 0) out[e] = 1.f / (1.f + expf(-w));
        }
    }
}

// ---------------------------------------------------------------------------
// Fallback path (proven-correct r2 kernels) in case cooperative launch is
// rejected by the runtime/graph-capture.
// ---------------------------------------------------------------------------
__global__ __launch_bounds__(256) void scan_rows(
    const float* __restrict__ adj, int* __restrict__ cnt, int* __restrict__ nbr)
{
    const int lane = threadIdx.x & 63;
    const int wid  = (blockIdx.x << 2) | (threadIdx.x >> 6);
    const int nw   = gridDim.x << 2;
    const unsigned long long lmask = (1ull << lane) - 1ull;

    for (int row = wid; row < NN; row += nw) {
        const fx4* rp  = (const fx4*)(adj + (size_t)row * NN);
        int* outp = nbr + (size_t)row * CAP;
        int base = 0;

        fx4 b0 = __builtin_nontemporal_load(&rp[lane]);
        fx4 b1 = __builtin_nontemporal_load(&rp[64  + lane]);
        fx4 b2 = __builtin_nontemporal_load(&rp[128 + lane]);
        fx4 b3 = __builtin_nontemporal_load(&rp[192 + lane]);

        #define CKCOMP(val, col)                                                  \
            { unsigned long long _b = __ballot((val) != 0.f);                     \
              if ((val) != 0.f) {                                                 \
                  int _p = base + (int)__popcll(_b & lmask);                      \
                  if (_p < CAP) outp[_p] = (col);                                 \
              }                                                                   \
              base += (int)__popcll(_b); }

        #define CKCHUNK(v, cidx)                                                  \
            { int _cb = (cidx) * 256 + lane * 4;                                  \
              CKCOMP(v.x, _cb); CKCOMP(v.y, _cb + 1);                             \
              CKCOMP(v.z, _cb + 2); CKCOMP(v.w, _cb + 3); }

        for (int cc = 0; cc < 40; cc += 4) {
            fx4 v0 = b0, v1 = b1, v2 = b2, v3 = b3;
            int n0 = (cc + 4) * 64 + lane;
            int n1 = (cc + 5) * 64 + lane;
            int n2 = (cc + 6) * 64 + lane;
            int n3 = (cc + 7) * 64 + lane;
            b0 = (n0 < 2500) ? __builtin_nontemporal_load(&rp[n0]) : (fx4){0.f,0.f,0.f,0.f};
            b1 = (n1 < 2500) ? __builtin_nontemporal_load(&rp[n1]) : (fx4){0.f,0.f,0.f,0.f};
            b2 = (n2 < 2500) ? __builtin_nontemporal_load(&rp[n2]) : (fx4){0.f,0.f,0.f,0.f};
            b3 = (n3 < 2500) ? __builtin_nontemporal_load(&rp[n3]) : (fx4){0.f,0.f,0.f,0.f};
            CKCHUNK(v0, cc);
            CKCHUNK(v1, cc + 1);
            CKCHUNK(v2, cc + 2);
            CKCHUNK(v3, cc + 3);
        }
        #undef CKCHUNK
        #undef CKCOMP

        if (lane == 0) cnt[row] = base;
    }
}

__global__ __launch_bounds__(256) void gather_rows(
    const float* __restrict__ emb, const int* __restrict__ cnt,
    const int* __restrict__ nbr, float* __restrict__ xn)
{
    const int i = blockIdx.x;
    const int t = threadIdx.x;
    __shared__ int   s_list[CAP];
    __shared__ float s_red[4];
    __shared__ float s_norm;

    const int c = cnt[i];
    const int m = (c < CAP) ? c : CAP;

    const float self = emb[(size_t)i * DD + t];
    if (t < m) s_list[t] = nbr[(size_t)i * CAP + t];
    __syncthreads();

    float a0=0.f,a1=0.f,a2=0.f,a3=0.f,a4=0.f,a5=0.f,a6=0.f,a7=0.f;
    int k = 0;
    for (; k + 8 <= m; k += 8) {
        int i0=s_list[k],   i1=s_list[k+1], i2=s_list[k+2], i3=s_list[k+3];
        int i4=s_list[k+4], i5=s_list[k+5], i6=s_list[k+6], i7=s_list[k+7];
        a0 += emb[(size_t)i0*DD + t]; a1 += emb[(size_t)i1*DD + t];
        a2 += emb[(size_t)i2*DD + t]; a3 += emb[(size_t)i3*DD + t];
        a4 += emb[(size_t)i4*DD + t]; a5 += emb[(size_t)i5*DD + t];
        a6 += emb[(size_t)i6*DD + t]; a7 += emb[(size_t)i7*DD + t];
    }
    for (; k < m; ++k) a0 += emb[(size_t)s_list[k]*DD + t];
    const float acc = ((a0+a1)+(a2+a3)) + ((a4+a5)+(a6+a7));

    const float deg = (float)c + 1e-6f;
    const float x = self + acc / deg;

    float s = x * x;
    #pragma unroll
    for (int o = 32; o > 0; o >>= 1) s += __shfl_down(s, o, 64);
    const int lane = t & 63, wvv = t >> 6;
    if (lane == 0) s_red[wvv] = s;
    __syncthreads();
    if (t == 0) {
        float tot = s_red[0] + s_red[1] + s_red[2] + s_red[3];
        s_norm = fmaxf(sqrtf(tot), 1e-8f);
    }
    __syncthreads();

    xn[(size_t)i * DD + t] = x / s_norm;
}

__global__ __launch_bounds__(64) void edge_weights(
    const int* __restrict__ edges, const float* __restrict__ xn,
    const int* __restrict__ cnt, const int* __restrict__ nbr,
    float* __restrict__ out)
{
    const int e = blockIdx.x;
    const int lane = threadIdx.x;
    const int srcI = edges[e];
    const int dstI = edges[QQ + e];

    __shared__ int s_dst[CAP];
    __shared__ int s_com[CAP];
    __shared__ int s_ncom;

    const int2 sA = ((const int2*)(nbr + (size_t)srcI * CAP))[lane];
    const int2 dA = ((const int2*)(nbr + (size_t)dstI * CAP))[lane];
    const int cs0 = cnt[srcI];
    const int cd0 = cnt[dstI];
    const int cs = (cs0 < CAP) ? cs0 : CAP;
    const int cd = (cd0 < CAP) ? cd0 : CAP;

    if (lane == 0) s_ncom = 0;
    s_dst[2 * lane]     = dA.x;
    s_dst[2 * lane + 1] = dA.y;
    __syncthreads();

    {
        int k0 = 2 * lane, k1 = 2 * lane + 1;
        if (k0 < cs) {
            bool f = false;
            for (int j = 0; j < cd; ++j) { if (s_dst[j] == sA.x) { f = true; break; } }
            if (f) { int p = atomicAdd(&s_ncom, 1); s_com[p] = sA.x; }
        }
        if (k1 < cs) {
            bool f = false;
            for (int j = 0; j < cd; ++j) { if (s_dst[j] == sA.y) { f = true; break; } }
            if (f) { int p = atomicAdd(&s_ncom, 1); s_com[p] = sA.y; }
        }
    }
    __syncthreads();

    const int nc = s_ncom;
    if (nc == 0) { if (lane == 0) out[e] = 0.5f; return; }

    const float4 vs = ((const float4*)(xn + (size_t)srcI * DD))[lane];
    const float4 vd = ((const float4*)(xn + (size_t)dstI * DD))[lane];

    float w = 0.f;
    for (int q = 0; q < nc; ++q) {
        const float4 vc = ((const float4*)(xn + (size_t)s_com[q] * DD))[lane];
        float a = vs.x*vc.x + vs.y*vc.y + vs.z*vc.z + vs.w*vc.w;
        float b = vd.x*vc.x + vd.y*vc.y + vd.z*vc.z + vd.w*vc.w;
        #pragma unroll
        for (int o = 32; o > 0; o >>= 1) {
            a += __shfl_xor(a, o, 64);
            b += __shfl_xor(b, o, 64);
        }
        w += a * b;
    }
    if (lane == 0) out[e] = 1.f / (1.f + expf(-w));
}

extern "C" void kernel_launch(void* const* d_in, const int* in_sizes, int n_in,
                              void* d_out, int out_size, void* d_ws, size_t ws_size,
                              hipStream_t stream) {
    const float* emb   = (const float*)d_in[0];   // [N, D] fp32
    const float* adj   = (const float*)d_in[1];   // [N, N] fp32 (0/1)
    const int*   edges = (const int*)d_in[2];     // [2, Q] int32
    float*       out   = (float*)d_out;           // [Q] fp32

    float* xn  = (float*)d_ws;
    int*   cnt = (int*)(xn + (size_t)NN * DD);
    int*   nbr = cnt + NN;

    void* args[] = { (void*)&emb, (void*)&adj, (void*)&edges, (void*)&out,
                     (void*)&xn, (void*)&cnt, (void*)&nbr };
    hipError_t err = hipLaunchCooperativeKernel((const void*)fused,
                                                dim3(NB), dim3(256),
                                                args, 0, stream);
    if (err != hipSuccess) {
        // fallback: proven 3-kernel path
        scan_rows<<<1024, 256, 0, stream>>>(adj, cnt, nbr);
        gather_rows<<<NN, 256, 0, stream>>>(emb, cnt, nbr, xn);
        edge_weights<<<QQ, 64, 0, stream>>>(edges, xn, cnt, nbr, out);
    }
}

// Round 5
// 665.249 us; speedup vs baseline: 1.5794x; 1.5794x over previous
//
#include <hip/hip_runtime.h>
#include <math.h>

#define NN 10000
#define DD 256
#define QQ 4096
#define CAP 128   // max neighbors kept per row; Binom(10000,0.003) tail @128 ~ 0

typedef float  fx4 __attribute__((ext_vector_type(4)));   // native vec for nontemporal builtin

// ws layout:
//   float xn[NN*DD]      normalized x rows
//   int   cnt[NN]        TRUE neighbor count per row (consumers clamp to CAP)
//   int   nbr[NN*CAP]    neighbor indices per row

// MEASUREMENT ROUND: scan_rows is launched 3x (idempotent). dur_us delta vs
// round-2 baseline (532us) = 2x scan time; if scan ~240us the three scan
// dispatches surface in rocprof top-5 with their counters.
__global__ __launch_bounds__(256) void scan_rows(
    const float* __restrict__ adj, int* __restrict__ cnt, int* __restrict__ nbr)
{
    const int lane = threadIdx.x & 63;
    const int wid  = (blockIdx.x << 2) | (threadIdx.x >> 6);
    const int nw   = gridDim.x << 2;
    const unsigned long long lmask = (1ull << lane) - 1ull;

    for (int row = wid; row < NN; row += nw) {
        const fx4* rp  = (const fx4*)(adj + (size_t)row * NN);   // 2500 fx4 per row
        int* outp = nbr + (size_t)row * CAP;
        int base = 0;   // wave-uniform running count (true count, may pass CAP)

        fx4 b0 = __builtin_nontemporal_load(&rp[lane]);
        fx4 b1 = __builtin_nontemporal_load(&rp[64  + lane]);
        fx4 b2 = __builtin_nontemporal_load(&rp[128 + lane]);
        fx4 b3 = __builtin_nontemporal_load(&rp[192 + lane]);

        #define CKCOMP(val, col)                                                  \
            { unsigned long long _b = __ballot((val) != 0.f);                     \
              if ((val) != 0.f) {                                                 \
                  int _p = base + (int)__popcll(_b & lmask);                      \
                  if (_p < CAP) outp[_p] = (col);                                 \
              }                                                                   \
              base += (int)__popcll(_b); }

        #define CKCHUNK(v, cidx)                                                  \
            { int _cb = (cidx) * 256 + lane * 4;                                  \
              CKCOMP(v.x, _cb); CKCOMP(v.y, _cb + 1);                             \
              CKCOMP(v.z, _cb + 2); CKCOMP(v.w, _cb + 3); }

        for (int cc = 0; cc < 40; cc += 4) {
            fx4 v0 = b0, v1 = b1, v2 = b2, v3 = b3;
            int n0 = (cc + 4) * 64 + lane;
            int n1 = (cc + 5) * 64 + lane;
            int n2 = (cc + 6) * 64 + lane;
            int n3 = (cc + 7) * 64 + lane;
            b0 = (n0 < 2500) ? __builtin_nontemporal_load(&rp[n0]) : (fx4){0.f,0.f,0.f,0.f};
            b1 = (n1 < 2500) ? __builtin_nontemporal_load(&rp[n1]) : (fx4){0.f,0.f,0.f,0.f};
            b2 = (n2 < 2500) ? __builtin_nontemporal_load(&rp[n2]) : (fx4){0.f,0.f,0.f,0.f};
            b3 = (n3 < 2500) ? __builtin_nontemporal_load(&rp[n3]) : (fx4){0.f,0.f,0.f,0.f};
            CKCHUNK(v0, cc);
            CKCHUNK(v1, cc + 1);
            CKCHUNK(v2, cc + 2);
            CKCHUNK(v3, cc + 3);
        }
        #undef CKCHUNK
        #undef CKCOMP

        if (lane == 0) cnt[row] = base;
    }
}

__global__ __launch_bounds__(256) void gather_rows(
    const float* __restrict__ emb, const int* __restrict__ cnt,
    const int* __restrict__ nbr, float* __restrict__ xn)
{
    const int i = blockIdx.x;
    const int t = threadIdx.x;            // t in [0,256) == dim index
    __shared__ int   s_list[CAP];
    __shared__ float s_red[4];
    __shared__ float s_norm;

    const int c = cnt[i];
    const int m = (c < CAP) ? c : CAP;

    const float self = emb[(size_t)i * DD + t];
    if (t < m) s_list[t] = nbr[(size_t)i * CAP + t];
    __syncthreads();

    float a0=0.f,a1=0.f,a2=0.f,a3=0.f,a4=0.f,a5=0.f,a6=0.f,a7=0.f;
    int k = 0;
    for (; k + 8 <= m; k += 8) {
        int i0=s_list[k],   i1=s_list[k+1], i2=s_list[k+2], i3=s_list[k+3];
        int i4=s_list[k+4], i5=s_list[k+5], i6=s_list[k+6], i7=s_list[k+7];
        a0 += emb[(size_t)i0*DD + t]; a1 += emb[(size_t)i1*DD + t];
        a2 += emb[(size_t)i2*DD + t]; a3 += emb[(size_t)i3*DD + t];
        a4 += emb[(size_t)i4*DD + t]; a5 += emb[(size_t)i5*DD + t];
        a6 += emb[(size_t)i6*DD + t]; a7 += emb[(size_t)i7*DD + t];
    }
    for (; k < m; ++k) a0 += emb[(size_t)s_list[k]*DD + t];
    const float acc = ((a0+a1)+(a2+a3)) + ((a4+a5)+(a6+a7));

    const float deg = (float)c + 1e-6f;
    const float x = self + acc / deg;

    float s = x * x;
    #pragma unroll
    for (int o = 32; o > 0; o >>= 1) s += __shfl_down(s, o, 64);
    const int lane = t & 63, wv = t >> 6;
    if (lane == 0) s_red[wv] = s;
    __syncthreads();
    if (t == 0) {
        float tot = s_red[0] + s_red[1] + s_red[2] + s_red[3];
        s_norm = fmaxf(sqrtf(tot), 1e-8f);
    }
    __syncthreads();

    xn[(size_t)i * DD + t] = x / s_norm;
}

__global__ __launch_bounds__(64) void edge_weights(
    const int* __restrict__ edges, const float* __restrict__ xn,
    const int* __restrict__ cnt, const int* __restrict__ nbr,
    float* __restrict__ out)
{
    const int e = blockIdx.x;
    const int lane = threadIdx.x;
    const int srcI = edges[e];
    const int dstI = edges[QQ + e];

    __shared__ int s_dst[CAP];
    __shared__ int s_com[CAP];
    __shared__ int s_ncom;

    const int2 sA = ((const int2*)(nbr + (size_t)srcI * CAP))[lane];  // src row, 2 entries/lane
    const int2 dA = ((const int2*)(nbr + (size_t)dstI * CAP))[lane];  // dst row
    const int cs0 = cnt[srcI];
    const int cd0 = cnt[dstI];
    const int cs = (cs0 < CAP) ? cs0 : CAP;   // cnt is TRUE count; clamp
    const int cd = (cd0 < CAP) ? cd0 : CAP;

    if (lane == 0) s_ncom = 0;
    s_dst[2 * lane]     = dA.x;
    s_dst[2 * lane + 1] = dA.y;
    __syncthreads();

    {
        int k0 = 2 * lane, k1 = 2 * lane + 1;
        if (k0 < cs) {
            bool f = false;
            for (int j = 0; j < cd; ++j) { if (s_dst[j] == sA.x) { f = true; break; } }
            if (f) { int p = atomicAdd(&s_ncom, 1); s_com[p] = sA.x; }
        }
        if (k1 < cs) {
            bool f = false;
            for (int j = 0; j < cd; ++j) { if (s_dst[j] == sA.y) { f = true; break; } }
            if (f) { int p = atomicAdd(&s_ncom, 1); s_com[p] = sA.y; }
        }
    }
    __syncthreads();

    const int nc = s_ncom;
    if (nc == 0) { if (lane == 0) out[e] = 0.5f; return; }

    const float4 vs = ((const float4*)(xn + (size_t)srcI * DD))[lane];
    const float4 vd = ((const float4*)(xn + (size_t)dstI * DD))[lane];

    float w = 0.f;
    for (int q = 0; q < nc; ++q) {
        const float4 vc = ((const float4*)(xn + (size_t)s_com[q] * DD))[lane];
        float a = vs.x*vc.x + vs.y*vc.y + vs.z*vc.z + vs.w*vc.w;
        float b = vd.x*vc.x + vd.y*vc.y + vd.z*vc.z + vd.w*vc.w;
        #pragma unroll
        for (int o = 32; o > 0; o >>= 1) {
            a += __shfl_xor(a, o, 64);
            b += __shfl_xor(b, o, 64);
        }
        w += a * b;
    }
    if (lane == 0) out[e] = 1.f / (1.f + expf(-w));
}

extern "C" void kernel_launch(void* const* d_in, const int* in_sizes, int n_in,
                              void* d_out, int out_size, void* d_ws, size_t ws_size,
                              hipStream_t stream) {
    const float* emb   = (const float*)d_in[0];   // [N, D] fp32
    const float* adj   = (const float*)d_in[1];   // [N, N] fp32 (0/1)
    const int*   edges = (const int*)d_in[2];     // [2, Q] int32
    float*       out   = (float*)d_out;           // [Q] fp32

    float* xn  = (float*)d_ws;
    int*   cnt = (int*)(xn + (size_t)NN * DD);
    int*   nbr = cnt + NN;

    // MEASUREMENT: 3x scan (idempotent). Delta vs r2 baseline = 2x scan time;
    // if scan is large its dispatches surface in rocprof top-5 with counters.
    scan_rows<<<1024, 256, 0, stream>>>(adj, cnt, nbr);
    scan_rows<<<1024, 256, 0, stream>>>(adj, cnt, nbr);
    scan_rows<<<1024, 256, 0, stream>>>(adj, cnt, nbr);
    gather_rows<<<NN, 256, 0, stream>>>(emb, cnt, nbr, xn);
    edge_weights<<<QQ, 64, 0, stream>>>(edges, xn, cnt, nbr, out);
}

// Round 6
// 537.994 us; speedup vs baseline: 1.9530x; 1.2365x over previous
//
#include <hip/hip_runtime.h>
#include <math.h>

#define NN 10000
#define DD 256
#define QQ 4096
#define CAP 128   // max neighbors kept per row; Binom(10000,0.003) tail @128 ~ 0

typedef float  fx4 __attribute__((ext_vector_type(4)));   // native vec for nontemporal builtin

// ws layout:
//   float xn[NN*DD]      normalized x rows
//   int   cnt[NN]        TRUE neighbor count per row (consumers clamp to CAP)
//   int   nbr[NN*CAP]    neighbor indices per row

// Phase 1 (measured 66us ~= 400MB streaming roofline — do not touch):
__global__ __launch_bounds__(256) void scan_rows(
    const float* __restrict__ adj, int* __restrict__ cnt, int* __restrict__ nbr)
{
    const int lane = threadIdx.x & 63;
    const int wid  = (blockIdx.x << 2) | (threadIdx.x >> 6);
    const int nw   = gridDim.x << 2;
    const unsigned long long lmask = (1ull << lane) - 1ull;

    for (int row = wid; row < NN; row += nw) {
        const fx4* rp  = (const fx4*)(adj + (size_t)row * NN);   // 2500 fx4 per row
        int* outp = nbr + (size_t)row * CAP;
        int base = 0;   // wave-uniform running count (true count, may pass CAP)

        fx4 b0 = __builtin_nontemporal_load(&rp[lane]);
        fx4 b1 = __builtin_nontemporal_load(&rp[64  + lane]);
        fx4 b2 = __builtin_nontemporal_load(&rp[128 + lane]);
        fx4 b3 = __builtin_nontemporal_load(&rp[192 + lane]);

        #define CKCOMP(val, col)                                                  \
            { unsigned long long _b = __ballot((val) != 0.f);                     \
              if ((val) != 0.f) {                                                 \
                  int _p = base + (int)__popcll(_b & lmask);                      \
                  if (_p < CAP) outp[_p] = (col);                                 \
              }                                                                   \
              base += (int)__popcll(_b); }

        #define CKCHUNK(v, cidx)                                                  \
            { int _cb = (cidx) * 256 + lane * 4;                                  \
              CKCOMP(v.x, _cb); CKCOMP(v.y, _cb + 1);                             \
              CKCOMP(v.z, _cb + 2); CKCOMP(v.w, _cb + 3); }

        for (int cc = 0; cc < 40; cc += 4) {
            fx4 v0 = b0, v1 = b1, v2 = b2, v3 = b3;
            int n0 = (cc + 4) * 64 + lane;
            int n1 = (cc + 5) * 64 + lane;
            int n2 = (cc + 6) * 64 + lane;
            int n3 = (cc + 7) * 64 + lane;
            b0 = (n0 < 2500) ? __builtin_nontemporal_load(&rp[n0]) : (fx4){0.f,0.f,0.f,0.f};
            b1 = (n1 < 2500) ? __builtin_nontemporal_load(&rp[n1]) : (fx4){0.f,0.f,0.f,0.f};
            b2 = (n2 < 2500) ? __builtin_nontemporal_load(&rp[n2]) : (fx4){0.f,0.f,0.f,0.f};
            b3 = (n3 < 2500) ? __builtin_nontemporal_load(&rp[n3]) : (fx4){0.f,0.f,0.f,0.f};
            CKCHUNK(v0, cc);
            CKCHUNK(v1, cc + 1);
            CKCHUNK(v2, cc + 2);
            CKCHUNK(v3, cc + 3);
        }
        #undef CKCHUNK
        #undef CKCOMP

        if (lane == 0) cnt[row] = base;
    }
}

// Phase 2 REWRITE (was ~210us, the dominant cost): wave-per-row, float4
// gathers. One wave covers the whole 256-float emb row per neighbor with a
// SINGLE instruction (64 lanes x 16B = 1KB) — 4x fewer lane-addresses than
// the old scalar gather (address-processing was the theorized limiter).
// Neighbor indices live one-per-lane in registers, broadcast via __shfl:
// no LDS, no __syncthreads. 8 float4 loads in flight per lane.
__global__ __launch_bounds__(256) void gather_rows(
    const float* __restrict__ emb, const int* __restrict__ cnt,
    const int* __restrict__ nbr, float* __restrict__ xn)
{
    const int lane = threadIdx.x & 63;
    const int w    = (blockIdx.x << 2) | (threadIdx.x >> 6);
    const int nw   = gridDim.x << 2;
    const float4* E = (const float4*)emb;     // row i = E[i*64 .. i*64+63]

    for (int row = w; row < NN; row += nw) {
        const int c = cnt[row];
        const int m = (c < CAP) ? c : CAP;

        const float4 self = E[(size_t)row * 64 + lane];

        // lane's neighbor slots (covers CAP=128 with two regs)
        const int my0 = (lane < m)      ? nbr[(size_t)row * CAP + lane]      : 0;
        const int my1 = (64 + lane < m) ? nbr[(size_t)row * CAP + 64 + lane] : 0;

        float ax = 0.f, ay = 0.f, az = 0.f, aw = 0.f;

        #define NIDX(J) __shfl(((J) < 64) ? my0 : my1, (J) & 63, 64)
        int j = 0;
        for (; j + 8 <= m; j += 8) {
            int i0 = NIDX(j),     i1 = NIDX(j + 1), i2 = NIDX(j + 2), i3 = NIDX(j + 3);
            int i4 = NIDX(j + 4), i5 = NIDX(j + 5), i6 = NIDX(j + 6), i7 = NIDX(j + 7);
            float4 v0 = E[(size_t)i0 * 64 + lane];
            float4 v1 = E[(size_t)i1 * 64 + lane];
            float4 v2 = E[(size_t)i2 * 64 + lane];
            float4 v3 = E[(size_t)i3 * 64 + lane];
            float4 v4 = E[(size_t)i4 * 64 + lane];
            float4 v5 = E[(size_t)i5 * 64 + lane];
            float4 v6 = E[(size_t)i6 * 64 + lane];
            float4 v7 = E[(size_t)i7 * 64 + lane];
            ax += ((v0.x + v1.x) + (v2.x + v3.x)) + ((v4.x + v5.x) + (v6.x + v7.x));
            ay += ((v0.y + v1.y) + (v2.y + v3.y)) + ((v4.y + v5.y) + (v6.y + v7.y));
            az += ((v0.z + v1.z) + (v2.z + v3.z)) + ((v4.z + v5.z) + (v6.z + v7.z));
            aw += ((v0.w + v1.w) + (v2.w + v3.w)) + ((v4.w + v5.w) + (v6.w + v7.w));
        }
        for (; j < m; ++j) {
            int i0 = NIDX(j);
            float4 v0 = E[(size_t)i0 * 64 + lane];
            ax += v0.x; ay += v0.y; az += v0.z; aw += v0.w;
        }
        #undef NIDX

        const float deg = (float)c + 1e-6f;
        const float xx = self.x + ax / deg;
        const float xy = self.y + ay / deg;
        const float xz = self.z + az / deg;
        const float xw = self.w + aw / deg;

        float s = xx * xx + xy * xy + xz * xz + xw * xw;
        #pragma unroll
        for (int o = 32; o > 0; o >>= 1) s += __shfl_xor(s, o, 64);
        const float inv = 1.f / fmaxf(sqrtf(s), 1e-8f);

        float4 r;
        r.x = xx * inv; r.y = xy * inv; r.z = xz * inv; r.w = xw * inv;
        ((float4*)xn)[(size_t)row * 64 + lane] = r;
    }
}

// Phase 3 (est. ~2-5us): unchanged.
__global__ __launch_bounds__(64) void edge_weights(
    const int* __restrict__ edges, const float* __restrict__ xn,
    const int* __restrict__ cnt, const int* __restrict__ nbr,
    float* __restrict__ out)
{
    const int e = blockIdx.x;
    const int lane = threadIdx.x;
    const int srcI = edges[e];
    const int dstI = edges[QQ + e];

    __shared__ int s_dst[CAP];
    __shared__ int s_com[CAP];
    __shared__ int s_ncom;

    const int2 sA = ((const int2*)(nbr + (size_t)srcI * CAP))[lane];  // src row, 2 entries/lane
    const int2 dA = ((const int2*)(nbr + (size_t)dstI * CAP))[lane];  // dst row
    const int cs0 = cnt[srcI];
    const int cd0 = cnt[dstI];
    const int cs = (cs0 < CAP) ? cs0 : CAP;   // cnt is TRUE count; clamp
    const int cd = (cd0 < CAP) ? cd0 : CAP;

    if (lane == 0) s_ncom = 0;
    s_dst[2 * lane]     = dA.x;
    s_dst[2 * lane + 1] = dA.y;
    __syncthreads();

    {
        int k0 = 2 * lane, k1 = 2 * lane + 1;
        if (k0 < cs) {
            bool f = false;
            for (int j = 0; j < cd; ++j) { if (s_dst[j] == sA.x) { f = true; break; } }
            if (f) { int p = atomicAdd(&s_ncom, 1); s_com[p] = sA.x; }
        }
        if (k1 < cs) {
            bool f = false;
            for (int j = 0; j < cd; ++j) { if (s_dst[j] == sA.y) { f = true; break; } }
            if (f) { int p = atomicAdd(&s_ncom, 1); s_com[p] = sA.y; }
        }
    }
    __syncthreads();

    const int nc = s_ncom;
    if (nc == 0) { if (lane == 0) out[e] = 0.5f; return; }

    const float4 vs = ((const float4*)(xn + (size_t)srcI * DD))[lane];
    const float4 vd = ((const float4*)(xn + (size_t)dstI * DD))[lane];

    float w = 0.f;
    for (int q = 0; q < nc; ++q) {
        const float4 vc = ((const float4*)(xn + (size_t)s_com[q] * DD))[lane];
        float a = vs.x*vc.x + vs.y*vc.y + vs.z*vc.z + vs.w*vc.w;
        float b = vd.x*vc.x + vd.y*vc.y + vd.z*vc.z + vd.w*vc.w;
        #pragma unroll
        for (int o = 32; o > 0; o >>= 1) {
            a += __shfl_xor(a, o, 64);
            b += __shfl_xor(b, o, 64);
        }
        w += a * b;
    }
    if (lane == 0) out[e] = 1.f / (1.f + expf(-w));
}

extern "C" void kernel_launch(void* const* d_in, const int* in_sizes, int n_in,
                              void* d_out, int out_size, void* d_ws, size_t ws_size,
                              hipStream_t stream) {
    const float* emb   = (const float*)d_in[0];   // [N, D] fp32
    const float* adj   = (const float*)d_in[1];   // [N, N] fp32 (0/1)
    const int*   edges = (const int*)d_in[2];     // [2, Q] int32
    float*       out   = (float*)d_out;           // [Q] fp32

    float* xn  = (float*)d_ws;
    int*   cnt = (int*)(xn + (size_t)NN * DD);
    int*   nbr = cnt + NN;

    scan_rows<<<1024, 256, 0, stream>>>(adj, cnt, nbr);
    gather_rows<<<2500, 256, 0, stream>>>(emb, cnt, nbr, xn);   // 1 row per wave
    edge_weights<<<QQ, 64, 0, stream>>>(edges, xn, cnt, nbr, out);
}

// Round 7
// 534.692 us; speedup vs baseline: 1.9651x; 1.0062x over previous
//
#include <hip/hip_runtime.h>
#include <math.h>

#define NN 10000
#define DD 256
#define QQ 4096
#define CAP 128   // max neighbors kept per row; Binom(10000,0.003) tail @128 ~ 0

typedef float  fx4 __attribute__((ext_vector_type(4)));   // native vec for nontemporal builtin

// ws layout:
//   float xn[NN*DD]      normalized x rows
//   int   cnt[NN]        TRUE neighbor count per row (consumers clamp to CAP)
//   int   nbr[NN*CAP]    neighbor indices per row
//
// Timing model (r0-r6 reconciled): dur = 245 (ws poison fill) + ~180 (harness
// restore overhead) + kernels. Kernels: scan 66us (HBM roofline, mandatory
// 400MB), gather ~30us (L3-bound 300MB), edges ~4us. This round overlaps the
// HBM-bound scan with the L3-bound gather INSIDE each wave (software pipeline
// across rows) — the two bandwidth domains currently serialize.

__global__ __launch_bounds__(256) void scan_gather(
    const float* __restrict__ adj, const float* __restrict__ emb,
    int* __restrict__ cnt, int* __restrict__ nbr, float* __restrict__ xn)
{
    const int lane = threadIdx.x & 63;
    const int wid  = (blockIdx.x << 2) | (threadIdx.x >> 6);
    const int nw   = gridDim.x << 2;
    const unsigned long long lmask = (1ull << lane) - 1ull;
    const float4* E = (const float4*)emb;     // row i = E[i*64 .. i*64+63]

    // pending-gather state for the PREVIOUS row (gathered while scanning the
    // current row; drained + normalized + stored at end of current row's scan)
    int pv = 0, prow = 0, pc = 0, pm = 0, pj = 0;
    int pmy0 = 0, pmy1 = 0;                   // prev row's nbr list, 2/lane
    float4 pself = {0.f, 0.f, 0.f, 0.f};
    float ax = 0.f, ay = 0.f, az = 0.f, aw = 0.f;

#define NIDX(J) __shfl(((J) < 64) ? pmy0 : pmy1, (J) & 63, 64)

#define GFIN()                                                                \
    {                                                                         \
        for (; pj + 4 <= pm; pj += 4) {                                       \
            const int i0 = NIDX(pj),     i1 = NIDX(pj + 1);                   \
            const int i2 = NIDX(pj + 2), i3 = NIDX(pj + 3);                   \
            float4 g0 = E[(size_t)i0 * 64 + lane];                            \
            float4 g1 = E[(size_t)i1 * 64 + lane];                            \
            float4 g2 = E[(size_t)i2 * 64 + lane];                            \
            float4 g3 = E[(size_t)i3 * 64 + lane];                            \
            ax += (g0.x + g1.x) + (g2.x + g3.x);                              \
            ay += (g0.y + g1.y) + (g2.y + g3.y);                              \
            az += (g0.z + g1.z) + (g2.z + g3.z);                              \
            aw += (g0.w + g1.w) + (g2.w + g3.w);                              \
        }                                                                     \
        for (; pj < pm; ++pj) {                                               \
            const int i0 = NIDX(pj);                                          \
            float4 g0 = E[(size_t)i0 * 64 + lane];                            \
            ax += g0.x; ay += g0.y; az += g0.z; aw += g0.w;                    \
        }                                                                     \
        const float deg = (float)pc + 1e-6f;                                  \
        const float xx = pself.x + ax / deg;                                  \
        const float xy = pself.y + ay / deg;                                  \
        const float xz = pself.z + az / deg;                                  \
        const float xw = pself.w + aw / deg;                                  \
        float s = xx * xx + xy * xy + xz * xz + xw * xw;                      \
        _Pragma("unroll")                                                     \
        for (int o = 32; o > 0; o >>= 1) s += __shfl_xor(s, o, 64);           \
        const float inv = 1.f / fmaxf(sqrtf(s), 1e-8f);                       \
        float4 r4;                                                            \
        r4.x = xx * inv; r4.y = xy * inv; r4.z = xz * inv; r4.w = xw * inv;   \
        ((float4*)xn)[(size_t)prow * 64 + lane] = r4;                         \
    }

    for (int row = wid; row < NN; row += nw) {
        const fx4* rp  = (const fx4*)(adj + (size_t)row * NN);   // 2500 fx4/row
        int* outp = nbr + (size_t)row * CAP;
        int base = 0;   // wave-uniform running count (true count, may pass CAP)

        fx4 b0 = __builtin_nontemporal_load(&rp[lane]);
        fx4 b1 = __builtin_nontemporal_load(&rp[64  + lane]);
        fx4 b2 = __builtin_nontemporal_load(&rp[128 + lane]);
        fx4 b3 = __builtin_nontemporal_load(&rp[192 + lane]);

#define CKCOMP(val, col)                                                      \
        { unsigned long long _b = __ballot((val) != 0.f);                     \
          if ((val) != 0.f) {                                                 \
              int _p = base + (int)__popcll(_b & lmask);                      \
              if (_p < CAP) outp[_p] = (col);                                 \
          }                                                                   \
          base += (int)__popcll(_b); }

#define CKCHUNK(v, cidx)                                                      \
        { int _cb = (cidx) * 256 + lane * 4;                                  \
          CKCOMP(v.x, _cb); CKCOMP(v.y, _cb + 1);                             \
          CKCOMP(v.z, _cb + 2); CKCOMP(v.w, _cb + 3); }

        for (int cc = 0; cc < 40; cc += 4) {
            fx4 v0 = b0, v1 = b1, v2 = b2, v3 = b3;

            // (1) issue prev-row gather batch FIRST. vmcnt retires in issue
            // order, so its wait at (4) leaves the newer scan prefetch (2)
            // outstanding — the HBM pipeline never drains. Branchless:
            // inactive iterations re-read L1-hot row 0 with weight 0.
            const bool  gact = (pv != 0) && (pj + 4 <= pm);
            const float gw   = gact ? 1.f : 0.f;
            const int   jj   = gact ? pj : 0;
            const int i0 = NIDX(jj),     i1 = NIDX(jj + 1);
            const int i2 = NIDX(jj + 2), i3 = NIDX(jj + 3);
            float4 g0 = E[(size_t)i0 * 64 + lane];
            float4 g1 = E[(size_t)i1 * 64 + lane];
            float4 g2 = E[(size_t)i2 * 64 + lane];
            float4 g3 = E[(size_t)i3 * 64 + lane];

            // (2) scan prefetch: next 4 chunks of this row (NT HBM stream)
            const int n0 = (cc + 4) * 64 + lane;
            const int n1 = (cc + 5) * 64 + lane;
            const int n2 = (cc + 6) * 64 + lane;
            const int n3 = (cc + 7) * 64 + lane;
            b0 = (n0 < 2500) ? __builtin_nontemporal_load(&rp[n0]) : (fx4){0.f,0.f,0.f,0.f};
            b1 = (n1 < 2500) ? __builtin_nontemporal_load(&rp[n1]) : (fx4){0.f,0.f,0.f,0.f};
            b2 = (n2 < 2500) ? __builtin_nontemporal_load(&rp[n2]) : (fx4){0.f,0.f,0.f,0.f};
            b3 = (n3 < 2500) ? __builtin_nontemporal_load(&rp[n3]) : (fx4){0.f,0.f,0.f,0.f};

            // (3) compact current chunks (waits only on v = older prefetch)
            CKCHUNK(v0, cc);
            CKCHUNK(v1, cc + 1);
            CKCHUNK(v2, cc + 2);
            CKCHUNK(v3, cc + 3);

            // (4) accumulate the gather batch (waits g, NOT the newer b's)
            ax = fmaf(gw, (g0.x + g1.x) + (g2.x + g3.x), ax);
            ay = fmaf(gw, (g0.y + g1.y) + (g2.y + g3.y), ay);
            az = fmaf(gw, (g0.z + g1.z) + (g2.z + g3.z), az);
            aw = fmaf(gw, (g0.w + g1.w) + (g2.w + g3.w), aw);
            pj += gact ? 4 : 0;
        }
#undef CKCHUNK
#undef CKCOMP

        // drain + finalize the previous row
        if (pv) GFIN();

        // hand the just-scanned row over as the new pending-gather row
        if (lane == 0) cnt[row] = base;
        pv = 1; prow = row; pc = base;
        pm = (base < CAP) ? base : CAP;
        pj = 0;
        pmy0 = (lane < pm)      ? outp[lane]      : 0;   // L2-hot re-read of own stores
        pmy1 = (64 + lane < pm) ? outp[64 + lane] : 0;
        pself = E[(size_t)row * 64 + lane];
        ax = ay = az = aw = 0.f;
    }

    // final pending row (not overlapped — ~1 of ~2.4 rows per wave)
    if (pv) GFIN();
#undef GFIN
#undef NIDX
}

// Phase 3 (~4us): unchanged.
__global__ __launch_bounds__(64) void edge_weights(
    const int* __restrict__ edges, const float* __restrict__ xn,
    const int* __restrict__ cnt, const int* __restrict__ nbr,
    float* __restrict__ out)
{
    const int e = blockIdx.x;
    const int lane = threadIdx.x;
    const int srcI = edges[e];
    const int dstI = edges[QQ + e];

    __shared__ int s_dst[CAP];
    __shared__ int s_com[CAP];
    __shared__ int s_ncom;

    const int2 sA = ((const int2*)(nbr + (size_t)srcI * CAP))[lane];  // src row, 2 entries/lane
    const int2 dA = ((const int2*)(nbr + (size_t)dstI * CAP))[lane];  // dst row
    const int cs0 = cnt[srcI];
    const int cd0 = cnt[dstI];
    const int cs = (cs0 < CAP) ? cs0 : CAP;   // cnt is TRUE count; clamp
    const int cd = (cd0 < CAP) ? cd0 : CAP;

    if (lane == 0) s_ncom = 0;
    s_dst[2 * lane]     = dA.x;
    s_dst[2 * lane + 1] = dA.y;
    __syncthreads();

    {
        int k0 = 2 * lane, k1 = 2 * lane + 1;
        if (k0 < cs) {
            bool f = false;
            for (int j = 0; j < cd; ++j) { if (s_dst[j] == sA.x) { f = true; break; } }
            if (f) { int p = atomicAdd(&s_ncom, 1); s_com[p] = sA.x; }
        }
        if (k1 < cs) {
            bool f = false;
            for (int j = 0; j < cd; ++j) { if (s_dst[j] == sA.y) { f = true; break; } }
            if (f) { int p = atomicAdd(&s_ncom, 1); s_com[p] = sA.y; }
        }
    }
    __syncthreads();

    const int nc = s_ncom;
    if (nc == 0) { if (lane == 0) out[e] = 0.5f; return; }

    const float4 vs = ((const float4*)(xn + (size_t)srcI * DD))[lane];
    const float4 vd = ((const float4*)(xn + (size_t)dstI * DD))[lane];

    float w = 0.f;
    for (int q = 0; q < nc; ++q) {
        const float4 vc = ((const float4*)(xn + (size_t)s_com[q] * DD))[lane];
        float a = vs.x*vc.x + vs.y*vc.y + vs.z*vc.z + vs.w*vc.w;
        float b = vd.x*vc.x + vd.y*vc.y + vd.z*vc.z + vd.w*vc.w;
        #pragma unroll
        for (int o = 32; o > 0; o >>= 1) {
            a += __shfl_xor(a, o, 64);
            b += __shfl_xor(b, o, 64);
        }
        w += a * b;
    }
    if (lane == 0) out[e] = 1.f / (1.f + expf(-w));
}

extern "C" void kernel_launch(void* const* d_in, const int* in_sizes, int n_in,
                              void* d_out, int out_size, void* d_ws, size_t ws_size,
                              hipStream_t stream) {
    const float* emb   = (const float*)d_in[0];   // [N, D] fp32
    const float* adj   = (const float*)d_in[1];   // [N, N] fp32 (0/1)
    const int*   edges = (const int*)d_in[2];     // [2, Q] int32
    float*       out   = (float*)d_out;           // [Q] fp32

    float* xn  = (float*)d_ws;
    int*   cnt = (int*)(xn + (size_t)NN * DD);
    int*   nbr = cnt + NN;

    // 1024 blocks x 4 waves: scan-BW-proven config; ~2.4 rows/wave -> ~60%
    // of gathers overlap the HBM scan stream.
    scan_gather<<<1024, 256, 0, stream>>>(adj, emb, cnt, nbr, xn);
    edge_weights<<<QQ, 64, 0, stream>>>(edges, xn, cnt, nbr, out);
}